// Round 2
// baseline (99.006 us; speedup 1.0000x reference)
//
#include <hip/hip_runtime.h>
#include <hip/hip_bf16.h>
#include <cstddef>

// Problem constants
#define DIMC   128
#define NHEADS 8
#define HDIM   16
#define DD     5
#define HH     24
#define WW_    48
#define NPOS   (DD * HH * WW_)     // 5760
#define SCALE  0.25f

typedef short    bf16x8 __attribute__((ext_vector_type(8)));
typedef float    f32x4  __attribute__((ext_vector_type(4)));
typedef unsigned u32x4  __attribute__((ext_vector_type(4)));

__device__ __forceinline__ unsigned short f2bf(float f) {
    unsigned u = __float_as_uint(f);
    u = (u + 0x7FFFu + ((u >> 16) & 1u)) >> 16;   // RNE
    return (unsigned short)u;
}
__device__ __forceinline__ float bf2f(unsigned short s) {
    return __uint_as_float(((unsigned)s) << 16);
}
// HW packed conversion: lo16 = bf16(a), hi16 = bf16(b), RNE. 1 VALU inst.
__device__ __forceinline__ unsigned cvt_pk_bf16(float a, float b) {
    unsigned r;
    asm("v_cvt_pk_bf16_f32 %0, %1, %2" : "=v"(r) : "v"(a), "v"(b));
    return r;
}
__device__ __forceinline__ float bfpk_lo(unsigned p) { return __uint_as_float(p << 16); }
__device__ __forceinline__ float bfpk_hi(unsigned p) { return __uint_as_float(p & 0xffff0000u); }
__device__ __forceinline__ bf16x8 pk4_to_bf16x8(unsigned a, unsigned b, unsigned c, unsigned d) {
    u32x4 t = {a, b, c, d};
    return __builtin_bit_cast(bf16x8, t);
}

// ---------------------------------------------------------------------------
// QKV GEMM with fused fp32->bf16 hi/lo conversion (v_cvt_pk_bf16_f32).
// C[M][384] = x[M][128] @ qkv_w[384][128]^T + b as 3-term bf16 split:
// hi*hi + lo*hi + hi*lo (missing lo*lo ~2^-18).
// ---------------------------------------------------------------------------
__global__ __launch_bounds__(256, 3) void gemm_qkv_kernel(
    const float* __restrict__ x,
    const float* __restrict__ wq,
    const float* __restrict__ qkv_b,
    unsigned short* __restrict__ Qhl,
    unsigned short* __restrict__ Kbf,
    unsigned short* __restrict__ Vbf)
{
    __shared__ __align__(16) unsigned short Bs[64][264];  // [hi128|lo128|pad8]

    const int tid = threadIdx.x;
    const int bn  = blockIdx.x * 64;
    const int bm  = blockIdx.y * 64;

    for (int i = tid; i < 2048; i += 256) {
        const int r = i >> 5, c4 = (i & 31) * 4;
        const float4 v = *(const float4*)(wq + (size_t)(bn + r) * 128 + c4);
        const unsigned h01 = cvt_pk_bf16(v.x, v.y);
        const unsigned h23 = cvt_pk_bf16(v.z, v.w);
        const unsigned l01 = cvt_pk_bf16(v.x - bfpk_lo(h01), v.y - bfpk_hi(h01));
        const unsigned l23 = cvt_pk_bf16(v.z - bfpk_lo(h23), v.w - bfpk_hi(h23));
        *(uint2*)(&Bs[r][c4])       = make_uint2(h01, h23);
        *(uint2*)(&Bs[r][128 + c4]) = make_uint2(l01, l23);
    }
    __syncthreads();

    const int w    = tid >> 6;
    const int lane = tid & 63;
    const int ln   = lane & 15;
    const int quad = lane >> 4;
    const int row  = bm + w * 16 + ln;
    const float* ar = x + (size_t)row * 128 + quad * 8;

    f32x4 acc[4] = {};
    #pragma unroll
    for (int kcg = 0; kcg < 4; ++kcg) {
        const float4 xa = *(const float4*)(ar + kcg * 32);
        const float4 xb = *(const float4*)(ar + kcg * 32 + 4);
        const unsigned h0 = cvt_pk_bf16(xa.x, xa.y);
        const unsigned h1 = cvt_pk_bf16(xa.z, xa.w);
        const unsigned h2 = cvt_pk_bf16(xb.x, xb.y);
        const unsigned h3 = cvt_pk_bf16(xb.z, xb.w);
        const unsigned l0 = cvt_pk_bf16(xa.x - bfpk_lo(h0), xa.y - bfpk_hi(h0));
        const unsigned l1 = cvt_pk_bf16(xa.z - bfpk_lo(h1), xa.w - bfpk_hi(h1));
        const unsigned l2 = cvt_pk_bf16(xb.x - bfpk_lo(h2), xb.y - bfpk_hi(h2));
        const unsigned l3 = cvt_pk_bf16(xb.z - bfpk_lo(h3), xb.w - bfpk_hi(h3));
        const bf16x8 ahi = pk4_to_bf16x8(h0, h1, h2, h3);
        const bf16x8 alo = pk4_to_bf16x8(l0, l1, l2, l3);
        #pragma unroll
        for (int nt = 0; nt < 4; ++nt) {
            const bf16x8 bhi = *(const bf16x8*)(&Bs[nt * 16 + ln][kcg * 32 + quad * 8]);
            const bf16x8 blo = *(const bf16x8*)(&Bs[nt * 16 + ln][128 + kcg * 32 + quad * 8]);
            acc[nt] = __builtin_amdgcn_mfma_f32_16x16x32_bf16(ahi, bhi, acc[nt], 0, 0, 0);
            acc[nt] = __builtin_amdgcn_mfma_f32_16x16x32_bf16(alo, bhi, acc[nt], 0, 0, 0);
            acc[nt] = __builtin_amdgcn_mfma_f32_16x16x32_bf16(ahi, blo, acc[nt], 0, 0, 0);
        }
    }

    #pragma unroll
    for (int nt = 0; nt < 4; ++nt) {
        const int col = bn + nt * 16 + ln;
        const float bv = qkv_b[col];
        #pragma unroll
        for (int r = 0; r < 4; ++r) {
            const int orow = bm + w * 16 + quad * 4 + r;
            const float val = acc[nt][r] + bv;
            if (col < 128) {               // q -> hi/lo pair
                const int h = col >> 4, ci = col & 15;
                const unsigned short hi = f2bf(val);
                Qhl[(size_t)orow * 256 + h * 32 + ci]      = hi;
                Qhl[(size_t)orow * 256 + h * 32 + 16 + ci] = f2bf(val - bf2f(hi));
            } else if (col < 256) {        // k -> bf16
                Kbf[(size_t)orow * 128 + (col - 128)] = f2bf(val);
            } else {                       // v -> bf16
                Vbf[(size_t)orow * 128 + (col - 256)] = f2bf(val);
            }
        }
    }
}

// ---------------------------------------------------------------------------
// Proj GEMM: out = ((O0+O1) * 1/(l0+l1)) @ proj_w^T + b.
// A built in-registers from attn's fp32 partials (combine + normalize +
// hi/lo split via cvt_pk); B converted fp32->hi|lo into LDS. Per kcg the 8
// fragment channels lie in ONE head: h = kcg*2 + (quad>>1) -> one scalar inv.
// Grid (2, 180) = 360 blocks of 128 thr.
// ---------------------------------------------------------------------------
__global__ __launch_bounds__(128, 2) void gemm_proj_kernel(
    const float* __restrict__ Opart,   // [2][5760][128] fp32 unnormalized
    const float* __restrict__ Lpart,   // [2][5760][8]   fp32 row-sums
    const float* __restrict__ wp,
    const float* __restrict__ proj_b,
    float* __restrict__ out)
{
    __shared__ __align__(16) unsigned short Bs[64][264];

    const int tid = threadIdx.x;
    const int bn  = blockIdx.x * 64;
    const int bm  = blockIdx.y * 32;

    for (int i = tid; i < 2048; i += 128) {
        const int r = i >> 5, c4 = (i & 31) * 4;
        const float4 v = *(const float4*)(wp + (size_t)(bn + r) * 128 + c4);
        const unsigned h01 = cvt_pk_bf16(v.x, v.y);
        const unsigned h23 = cvt_pk_bf16(v.z, v.w);
        const unsigned l01 = cvt_pk_bf16(v.x - bfpk_lo(h01), v.y - bfpk_hi(h01));
        const unsigned l23 = cvt_pk_bf16(v.z - bfpk_lo(h23), v.w - bfpk_hi(h23));
        *(uint2*)(&Bs[r][c4])       = make_uint2(h01, h23);
        *(uint2*)(&Bs[r][128 + c4]) = make_uint2(l01, l23);
    }
    __syncthreads();

    const int w    = tid >> 6;
    const int lane = tid & 63;
    const int ln   = lane & 15;
    const int quad = lane >> 4;
    const int row  = bm + w * 16 + ln;

    float linv[8];
    {
        const float4 l0a = *(const float4*)(Lpart + (size_t)row * 8);
        const float4 l0b = *(const float4*)(Lpart + (size_t)row * 8 + 4);
        const float4 l1a = *(const float4*)(Lpart + (size_t)(NPOS + row) * 8);
        const float4 l1b = *(const float4*)(Lpart + (size_t)(NPOS + row) * 8 + 4);
        linv[0] = 1.0f / (l0a.x + l1a.x); linv[1] = 1.0f / (l0a.y + l1a.y);
        linv[2] = 1.0f / (l0a.z + l1a.z); linv[3] = 1.0f / (l0a.w + l1a.w);
        linv[4] = 1.0f / (l0b.x + l1b.x); linv[5] = 1.0f / (l0b.y + l1b.y);
        linv[6] = 1.0f / (l0b.z + l1b.z); linv[7] = 1.0f / (l0b.w + l1b.w);
    }
    const float* o0 = Opart + (size_t)row * 128 + quad * 8;
    const float* o1 = o0 + (size_t)NPOS * 128;

    f32x4 acc[4] = {};
    #pragma unroll
    for (int kcg = 0; kcg < 4; ++kcg) {
        const float4 a0 = *(const float4*)(o0 + kcg * 32);
        const float4 a0b = *(const float4*)(o0 + kcg * 32 + 4);
        const float4 a1 = *(const float4*)(o1 + kcg * 32);
        const float4 a1b = *(const float4*)(o1 + kcg * 32 + 4);
        const float inv = linv[kcg * 2 + (quad >> 1)];
        const float v0 = (a0.x + a1.x) * inv,  v1 = (a0.y + a1.y) * inv;
        const float v2 = (a0.z + a1.z) * inv,  v3 = (a0.w + a1.w) * inv;
        const float v4 = (a0b.x + a1b.x) * inv, v5 = (a0b.y + a1b.y) * inv;
        const float v6 = (a0b.z + a1b.z) * inv, v7 = (a0b.w + a1b.w) * inv;
        const unsigned h0 = cvt_pk_bf16(v0, v1);
        const unsigned h1 = cvt_pk_bf16(v2, v3);
        const unsigned h2 = cvt_pk_bf16(v4, v5);
        const unsigned h3 = cvt_pk_bf16(v6, v7);
        const unsigned l0 = cvt_pk_bf16(v0 - bfpk_lo(h0), v1 - bfpk_hi(h0));
        const unsigned l1 = cvt_pk_bf16(v2 - bfpk_lo(h1), v3 - bfpk_hi(h1));
        const unsigned l2 = cvt_pk_bf16(v4 - bfpk_lo(h2), v5 - bfpk_hi(h2));
        const unsigned l3 = cvt_pk_bf16(v6 - bfpk_lo(h3), v7 - bfpk_hi(h3));
        const bf16x8 ahi = pk4_to_bf16x8(h0, h1, h2, h3);
        const bf16x8 alo = pk4_to_bf16x8(l0, l1, l2, l3);
        #pragma unroll
        for (int nt = 0; nt < 4; ++nt) {
            const bf16x8 bhi = *(const bf16x8*)(&Bs[nt * 16 + ln][kcg * 32 + quad * 8]);
            const bf16x8 blo = *(const bf16x8*)(&Bs[nt * 16 + ln][128 + kcg * 32 + quad * 8]);
            acc[nt] = __builtin_amdgcn_mfma_f32_16x16x32_bf16(ahi, bhi, acc[nt], 0, 0, 0);
            acc[nt] = __builtin_amdgcn_mfma_f32_16x16x32_bf16(alo, bhi, acc[nt], 0, 0, 0);
            acc[nt] = __builtin_amdgcn_mfma_f32_16x16x32_bf16(ahi, blo, acc[nt], 0, 0, 0);
        }
    }

    #pragma unroll
    for (int nt = 0; nt < 4; ++nt) {
        const int col = bn + nt * 16 + ln;
        const float bv = proj_b[col];
        #pragma unroll
        for (int r = 0; r < 4; ++r) {
            const int orow = bm + w * 16 + quad * 4 + r;
            out[(size_t)orow * 128 + col] = acc[nt][r] + bv;
        }
    }
}

// ---------------------------------------------------------------------------
// Fused neighborhood attention: u-range split across 2 blocks.
// Grid (144, 8): tile = bx>>1, half = bx&1. Block covers u in
// [half*256, half*256+256); 4 waves x 2 chunks of 32 each. Output:
// UNNORMALIZED fp32 O partials + l row-sums; proj combines and normalizes.
// 1152 blocks = 4.5/CU; LDS 26.4 KB.
// ---------------------------------------------------------------------------
__global__ __launch_bounds__(256, 4) void attn_kernel(
    const unsigned short* __restrict__ Qhl,   // [5760][256] bf16 per-head hi|lo
    const unsigned short* __restrict__ Kbf,   // [5760][128] bf16
    const unsigned short* __restrict__ Vbf,   // [5760][128] bf16
    float* __restrict__ Opart,                // [2][5760][128] fp32
    float* __restrict__ Lpart)                // [2][5760][8]   fp32
{
    // LDS layout:
    //   Vt   : ushort[16][264]  @     0   (8448 B)  V^T for this u-half
    //   Qb   : ushort[80][40]   @  8448   (6400 B)
    //   Pw   : ushort[4][2][16][40] @ 14848 (10240 B)
    //   red_l: float[4][80]     @ 25088   (1280 B)
    //   redO : float[4*5*16][16] @ 0      (20480 B) overlay post-barrier
    __shared__ __align__(16) char smem[26368];
    unsigned short (*Vt)[264] = (unsigned short(*)[264])smem;
    unsigned short (*Qb)[40]  = (unsigned short(*)[40])(smem + 8448);
    unsigned short* PwBase    = (unsigned short*)(smem + 14848);
    float* red_l              = (float*)(smem + 25088);
    float* redO               = (float*)smem;

    const int bx   = blockIdx.x;
    const int tile = bx >> 1;
    const int half = bx & 1;
    const int h    = blockIdx.y;
    const int ty0  = (tile / 12) * 4;
    const int tx0  = (tile % 12) * 4;
    const int tid  = threadIdx.x;

    // ---- stage V^T for this half's 256 u ----
    for (int i = tid; i < 512; i += 256) {
        const int ul = i >> 1, hf8 = i & 1;
        const int u  = half * 256 + ul;
        if (u < 500) {
            const int dp = u / 100;
            const int rr = u - dp * 100;
            const int yy = rr / 10;
            const int xx = rr - yy * 10;
            int y = ty0 - 3 + yy; if (y < 0) y += HH;  if (y >= HH) y -= HH;
            int x = tx0 - 3 + xx; if (x < 0) x += WW_; if (x >= WW_) x -= WW_;
            const int g = (dp * HH + y) * WW_ + x;
            const bf16x8 v = *(const bf16x8*)(Vbf + (size_t)g * 128 + h * 16 + hf8 * 8);
            #pragma unroll
            for (int c = 0; c < 8; ++c) Vt[hf8 * 8 + c][ul] = (unsigned short)v[c];
        } else {
            #pragma unroll
            for (int c = 0; c < 8; ++c) Vt[hf8 * 8 + c][ul] = 0;
        }
    }
    // ---- stage Q tile (straight bf16 copy) ----
    for (int i = tid; i < 320; i += 256) {
        const int p = i >> 2, seg = i & 3;
        const int d = p >> 4, s = p & 15;
        const int sy = s >> 2, sx = s & 3;
        const int g = (d * HH + ty0 + sy) * WW_ + tx0 + sx;
        *(bf16x8*)(&Qb[p][seg * 8]) = *(const bf16x8*)(Qhl + (size_t)g * 256 + h * 32 + seg * 8);
    }
    __syncthreads();

    const int w    = tid >> 6;
    const int lane = tid & 63;
    const int ln   = lane & 15;
    const int quad = lane >> 4;
    const int sy   = ln >> 2, sx = ln & 3;

    unsigned short* Pw = PwBase + w * 1280;  // [2][16][40]

    bf16x8 qf[5];
    #pragma unroll
    for (int mt = 0; mt < 5; ++mt)
        qf[mt] = *(const bf16x8*)(&Qb[mt * 16 + ln][quad * 8]);

    f32x4 Ow[5] = {};
    float lsum[5] = {};

    #pragma unroll
    for (int chunk = 0; chunk < 2; ++chunk) {
        const int u0g = (half * 8 + w * 2 + chunk) * 32;   // global u base
        const int u0l = (w * 2 + chunk) * 32;              // LDS-local u base

        int rowa, rowb;
        {
            const int ua = u0g + ln      < 500 ? u0g + ln      : 499;
            const int ub = u0g + 16 + ln < 500 ? u0g + 16 + ln : 499;
            int dp = ua / 100, rr = ua - dp * 100, yy = rr / 10, xx = rr - yy * 10;
            int y = ty0 - 3 + yy; if (y < 0) y += HH;  if (y >= HH) y -= HH;
            int x = tx0 - 3 + xx; if (x < 0) x += WW_; if (x >= WW_) x -= WW_;
            rowa = (dp * HH + y) * WW_ + x;
            dp = ub / 100; rr = ub - dp * 100; yy = rr / 10; xx = rr - yy * 10;
            y = ty0 - 3 + yy; if (y < 0) y += HH;  if (y >= HH) y -= HH;
            x = tx0 - 3 + xx; if (x < 0) x += WW_; if (x >= WW_) x -= WW_;
            rowb = (dp * HH + y) * WW_ + x;
        }
        const bf16x8 ka = *(const bf16x8*)(Kbf + (size_t)rowa * 128 + h * 16 + (quad & 1) * 8);
        const bf16x8 kb = *(const bf16x8*)(Kbf + (size_t)rowb * 128 + h * 16 + (quad & 1) * 8);

        bool msk[2][4];
        #pragma unroll
        for (int b = 0; b < 2; ++b)
            #pragma unroll
            for (int r = 0; r < 4; ++r) {
                const int u = u0g + 16 * b + 4 * quad + r;
                const int rr = u % 100;
                const int uy = rr / 10, ux = rr - uy * 10;
                msk[b][r] = (u < 500) && ((unsigned)(uy - sy) <= 6u)
                                      && ((unsigned)(ux - sx) <= 6u);
            }

        const bf16x8 vf = *(const bf16x8*)(&Vt[ln][u0l + quad * 8]);

        #pragma unroll
        for (int mt = 0; mt < 5; ++mt) {
            f32x4 s0 = __builtin_amdgcn_mfma_f32_16x16x32_bf16(
                ka, qf[mt], (f32x4){0.f, 0.f, 0.f, 0.f}, 0, 0, 0);
            f32x4 s1 = __builtin_amdgcn_mfma_f32_16x16x32_bf16(
                kb, qf[mt], (f32x4){0.f, 0.f, 0.f, 0.f}, 0, 0, 0);

            unsigned short* pw = Pw + (mt & 1) * 640 + ln * 40;
            #pragma unroll
            for (int b = 0; b < 2; ++b) {
                const f32x4 s = b ? s1 : s0;
                float ev[4];
                #pragma unroll
                for (int r = 0; r < 4; ++r)
                    ev[r] = msk[b][r] ? __expf(fmaf(s[r], SCALE, -8.0f)) : 0.f;
                const unsigned p01 = cvt_pk_bf16(ev[0], ev[1]);
                const unsigned p23 = cvt_pk_bf16(ev[2], ev[3]);
                lsum[mt] += bfpk_lo(p01) + bfpk_hi(p01) + bfpk_lo(p23) + bfpk_hi(p23);
                *(unsigned*)(pw + 16 * b + 4 * quad)     = p01;
                *(unsigned*)(pw + 16 * b + 4 * quad + 2) = p23;
            }
            const bf16x8 pf = *(const bf16x8*)(Pw + (mt & 1) * 640 + ln * 40 + quad * 8);
            Ow[mt] = __builtin_amdgcn_mfma_f32_16x16x32_bf16(vf, pf, Ow[mt], 0, 0, 0);
        }
    }

    // l: lanes (ln, quad) hold disjoint u-partials -> reduce across quads
    #pragma unroll
    for (int mt = 0; mt < 5; ++mt) {
        lsum[mt] += __shfl_xor(lsum[mt], 16);
        lsum[mt] += __shfl_xor(lsum[mt], 32);
    }

    __syncthreads();   // all Vt/Qb/Pw reads done; safe to overlay redO

    if (quad == 0) {
        #pragma unroll
        for (int mt = 0; mt < 5; ++mt)
            red_l[w * 80 + mt * 16 + ln] = lsum[mt];
    }
    #pragma unroll
    for (int mt = 0; mt < 5; ++mt)
        #pragma unroll
        for (int r = 0; r < 4; ++r)
            redO[(size_t)((w * 5 + mt) * 16 + quad * 4 + r) * 16 + ln] = Ow[mt][r];
    __syncthreads();

    // final: sum 4 wave-partials, write fp32 partials (no division)
    for (int i = tid; i < 1280; i += 256) {
        const int m = i >> 4, c = i & 15;
        const int mt = m >> 4, mloc = m & 15;
        float o = 0.f, l = 0.f;
        #pragma unroll
        for (int w4 = 0; w4 < 4; ++w4) {
            o += redO[(size_t)((w4 * 5 + mt) * 16 + c) * 16 + mloc];
            l += red_l[w4 * 80 + m];
        }
        const int qsy = (mloc >> 2), qsx = mloc & 3;
        const size_t g = (size_t)((mt * HH + ty0 + qsy) * WW_ + (tx0 + qsx));
        Opart[((size_t)half * NPOS + g) * 128 + h * HDIM + c] = o;
        if (c == 0) Lpart[((size_t)half * NPOS + g) * 8 + h] = l;
    }
}

// ---------------------------------------------------------------------------
extern "C" void kernel_launch(void* const* d_in, const int* in_sizes, int n_in,
                              void* d_out, int out_size, void* d_ws, size_t ws_size,
                              hipStream_t stream)
{
    const float* x      = (const float*)d_in[0];
    const float* qkv_w  = (const float*)d_in[1];
    const float* qkv_b  = (const float*)d_in[2];
    const float* proj_w = (const float*)d_in[3];
    const float* proj_b = (const float*)d_in[4];
    float* out = (float*)d_out;

    char* ws = (char*)d_ws;
    unsigned short* Qhl   = (unsigned short*)ws;  ws += (size_t)NPOS * 256 * 2;
    unsigned short* Kbf   = (unsigned short*)ws;  ws += (size_t)NPOS * 128 * 2;
    unsigned short* Vbf   = (unsigned short*)ws;  ws += (size_t)NPOS * 128 * 2;
    float*          Opart = (float*)ws;           ws += (size_t)2 * NPOS * 128 * 4;
    float*          Lpart = (float*)ws;           ws += (size_t)2 * NPOS * 8 * 4;

    // 1. QKV GEMM (fused fp32->hi/lo conversion) -> Qhl, Kbf, Vbf
    {
        dim3 grid(384 / 64, NPOS / 64);
        gemm_qkv_kernel<<<grid, 256, 0, stream>>>(x, qkv_w, qkv_b, Qhl, Kbf, Vbf);
    }
    // 2. fused neighborhood attention (u-split, 1152 blocks) -> Opart/Lpart
    {
        dim3 grid(144, NHEADS);
        attn_kernel<<<grid, 256, 0, stream>>>(Qhl, Kbf, Vbf, Opart, Lpart);
    }
    // 3. proj GEMM (combine halves + normalize + GEMM) -> out
    {
        dim3 grid(DIMC / 64, NPOS / 32);
        gemm_proj_kernel<<<grid, 128, 0, stream>>>(Opart, Lpart, proj_w, proj_b, out);
    }
}

// Round 3
// 95.065 us; speedup vs baseline: 1.0415x; 1.0415x over previous
//
#include <hip/hip_runtime.h>
#include <hip/hip_bf16.h>
#include <cstddef>

// Problem constants
#define DIMC   128
#define NHEADS 8
#define HDIM   16
#define DD     5
#define HH     24
#define WW_    48
#define NPOS   (DD * HH * WW_)     // 5760
#define SCALE  0.25f

typedef short    bf16x8 __attribute__((ext_vector_type(8)));
typedef float    f32x4  __attribute__((ext_vector_type(4)));
typedef unsigned u32x4  __attribute__((ext_vector_type(4)));

__device__ __forceinline__ unsigned short f2bf(float f) {
    unsigned u = __float_as_uint(f);
    u = (u + 0x7FFFu + ((u >> 16) & 1u)) >> 16;   // RNE
    return (unsigned short)u;
}
__device__ __forceinline__ float bf2f(unsigned short s) {
    return __uint_as_float(((unsigned)s) << 16);
}
// HW packed conversion: lo16 = bf16(a), hi16 = bf16(b), RNE. 1 VALU inst.
__device__ __forceinline__ unsigned cvt_pk_bf16(float a, float b) {
    unsigned r;
    asm("v_cvt_pk_bf16_f32 %0, %1, %2" : "=v"(r) : "v"(a), "v"(b));
    return r;
}
__device__ __forceinline__ float bfpk_lo(unsigned p) { return __uint_as_float(p << 16); }
__device__ __forceinline__ float bfpk_hi(unsigned p) { return __uint_as_float(p & 0xffff0000u); }
__device__ __forceinline__ bf16x8 pk4_to_bf16x8(unsigned a, unsigned b, unsigned c, unsigned d) {
    u32x4 t = {a, b, c, d};
    return __builtin_bit_cast(bf16x8, t);
}

// ---------------------------------------------------------------------------
// QKV GEMM with fused fp32->bf16 hi/lo conversion (v_cvt_pk_bf16_f32).
// C[M][384] = x[M][128] @ qkv_w[384][128]^T + b as 3-term bf16 split:
// hi*hi + lo*hi + hi*lo (missing lo*lo ~2^-18).
// ---------------------------------------------------------------------------
__global__ __launch_bounds__(256, 3) void gemm_qkv_kernel(
    const float* __restrict__ x,
    const float* __restrict__ wq,
    const float* __restrict__ qkv_b,
    unsigned short* __restrict__ Qhl,
    unsigned short* __restrict__ Kbf,
    unsigned short* __restrict__ Vbf)
{
    __shared__ __align__(16) unsigned short Bs[64][264];  // [hi128|lo128|pad8]

    const int tid = threadIdx.x;
    const int bn  = blockIdx.x * 64;
    const int bm  = blockIdx.y * 64;

    for (int i = tid; i < 2048; i += 256) {
        const int r = i >> 5, c4 = (i & 31) * 4;
        const float4 v = *(const float4*)(wq + (size_t)(bn + r) * 128 + c4);
        const unsigned h01 = cvt_pk_bf16(v.x, v.y);
        const unsigned h23 = cvt_pk_bf16(v.z, v.w);
        const unsigned l01 = cvt_pk_bf16(v.x - bfpk_lo(h01), v.y - bfpk_hi(h01));
        const unsigned l23 = cvt_pk_bf16(v.z - bfpk_lo(h23), v.w - bfpk_hi(h23));
        *(uint2*)(&Bs[r][c4])       = make_uint2(h01, h23);
        *(uint2*)(&Bs[r][128 + c4]) = make_uint2(l01, l23);
    }
    __syncthreads();

    const int w    = tid >> 6;
    const int lane = tid & 63;
    const int ln   = lane & 15;
    const int quad = lane >> 4;
    const int row  = bm + w * 16 + ln;
    const float* ar = x + (size_t)row * 128 + quad * 8;

    f32x4 acc[4] = {};
    #pragma unroll
    for (int kcg = 0; kcg < 4; ++kcg) {
        const float4 xa = *(const float4*)(ar + kcg * 32);
        const float4 xb = *(const float4*)(ar + kcg * 32 + 4);
        const unsigned h0 = cvt_pk_bf16(xa.x, xa.y);
        const unsigned h1 = cvt_pk_bf16(xa.z, xa.w);
        const unsigned h2 = cvt_pk_bf16(xb.x, xb.y);
        const unsigned h3 = cvt_pk_bf16(xb.z, xb.w);
        const unsigned l0 = cvt_pk_bf16(xa.x - bfpk_lo(h0), xa.y - bfpk_hi(h0));
        const unsigned l1 = cvt_pk_bf16(xa.z - bfpk_lo(h1), xa.w - bfpk_hi(h1));
        const unsigned l2 = cvt_pk_bf16(xb.x - bfpk_lo(h2), xb.y - bfpk_hi(h2));
        const unsigned l3 = cvt_pk_bf16(xb.z - bfpk_lo(h3), xb.w - bfpk_hi(h3));
        const bf16x8 ahi = pk4_to_bf16x8(h0, h1, h2, h3);
        const bf16x8 alo = pk4_to_bf16x8(l0, l1, l2, l3);
        #pragma unroll
        for (int nt = 0; nt < 4; ++nt) {
            const bf16x8 bhi = *(const bf16x8*)(&Bs[nt * 16 + ln][kcg * 32 + quad * 8]);
            const bf16x8 blo = *(const bf16x8*)(&Bs[nt * 16 + ln][128 + kcg * 32 + quad * 8]);
            acc[nt] = __builtin_amdgcn_mfma_f32_16x16x32_bf16(ahi, bhi, acc[nt], 0, 0, 0);
            acc[nt] = __builtin_amdgcn_mfma_f32_16x16x32_bf16(alo, bhi, acc[nt], 0, 0, 0);
            acc[nt] = __builtin_amdgcn_mfma_f32_16x16x32_bf16(ahi, blo, acc[nt], 0, 0, 0);
        }
    }

    #pragma unroll
    for (int nt = 0; nt < 4; ++nt) {
        const int col = bn + nt * 16 + ln;
        const float bv = qkv_b[col];
        #pragma unroll
        for (int r = 0; r < 4; ++r) {
            const int orow = bm + w * 16 + quad * 4 + r;
            const float val = acc[nt][r] + bv;
            if (col < 128) {               // q -> hi/lo pair
                const int h = col >> 4, ci = col & 15;
                const unsigned short hi = f2bf(val);
                Qhl[(size_t)orow * 256 + h * 32 + ci]      = hi;
                Qhl[(size_t)orow * 256 + h * 32 + 16 + ci] = f2bf(val - bf2f(hi));
            } else if (col < 256) {        // k -> bf16
                Kbf[(size_t)orow * 128 + (col - 128)] = f2bf(val);
            } else {                       // v -> bf16
                Vbf[(size_t)orow * 128 + (col - 256)] = f2bf(val);
            }
        }
    }
}

// ---------------------------------------------------------------------------
// Proj GEMM: out = Ahl @ proj_w^T + b, A pre-normalized bf16 hi/lo from attn.
// Per kcg, the 8 A-fragment channels (k = kcg*32 + quad*8 + j) lie in one
// head h = kcg*2 + (quad>>1), ci0 = (quad&1)*8 -> direct 16B hi/lo loads.
// Grid (2, 90) = 180 blocks of 256 thr.
// ---------------------------------------------------------------------------
__global__ __launch_bounds__(256, 3) void gemm_proj_kernel(
    const unsigned short* __restrict__ Ahl,   // [5760][256] bf16 per-head hi|lo
    const float* __restrict__ wp,
    const float* __restrict__ proj_b,
    float* __restrict__ out)
{
    __shared__ __align__(16) unsigned short Bs[64][264];

    const int tid = threadIdx.x;
    const int bn  = blockIdx.x * 64;
    const int bm  = blockIdx.y * 64;

    for (int i = tid; i < 2048; i += 256) {
        const int r = i >> 5, c4 = (i & 31) * 4;
        const float4 v = *(const float4*)(wp + (size_t)(bn + r) * 128 + c4);
        const unsigned h01 = cvt_pk_bf16(v.x, v.y);
        const unsigned h23 = cvt_pk_bf16(v.z, v.w);
        const unsigned l01 = cvt_pk_bf16(v.x - bfpk_lo(h01), v.y - bfpk_hi(h01));
        const unsigned l23 = cvt_pk_bf16(v.z - bfpk_lo(h23), v.w - bfpk_hi(h23));
        *(uint2*)(&Bs[r][c4])       = make_uint2(h01, h23);
        *(uint2*)(&Bs[r][128 + c4]) = make_uint2(l01, l23);
    }
    __syncthreads();

    const int w    = tid >> 6;
    const int lane = tid & 63;
    const int ln   = lane & 15;
    const int quad = lane >> 4;
    const int row  = bm + w * 16 + ln;
    // A base: head-block (quad>>1)*32, hi/lo sub-block (quad&1)*8
    const unsigned short* ar = Ahl + (size_t)row * 256 + (quad >> 1) * 32 + (quad & 1) * 8;

    f32x4 acc[4] = {};
    #pragma unroll
    for (int kcg = 0; kcg < 4; ++kcg) {
        const bf16x8 ahi = *(const bf16x8*)(ar + kcg * 64);
        const bf16x8 alo = *(const bf16x8*)(ar + kcg * 64 + 16);
        #pragma unroll
        for (int nt = 0; nt < 4; ++nt) {
            const bf16x8 bhi = *(const bf16x8*)(&Bs[nt * 16 + ln][kcg * 32 + quad * 8]);
            const bf16x8 blo = *(const bf16x8*)(&Bs[nt * 16 + ln][128 + kcg * 32 + quad * 8]);
            acc[nt] = __builtin_amdgcn_mfma_f32_16x16x32_bf16(ahi, bhi, acc[nt], 0, 0, 0);
            acc[nt] = __builtin_amdgcn_mfma_f32_16x16x32_bf16(alo, bhi, acc[nt], 0, 0, 0);
            acc[nt] = __builtin_amdgcn_mfma_f32_16x16x32_bf16(ahi, blo, acc[nt], 0, 0, 0);
        }
    }

    #pragma unroll
    for (int nt = 0; nt < 4; ++nt) {
        const int col = bn + nt * 16 + ln;
        const float bv = proj_b[col];
        #pragma unroll
        for (int r = 0; r < 4; ++r) {
            const int orow = bm + w * 16 + quad * 4 + r;
            out[(size_t)orow * 128 + col] = acc[nt][r] + bv;
        }
    }
}

// ---------------------------------------------------------------------------
// Fused neighborhood attention, FULL u-range per block (no half split).
// Grid (72, 8) = 576 blocks of 256 thr -> all co-resident (4/CU cap), no
// straggler round. 4 waves x 4 chunks of 32 u = 512 slots (500 real).
// Block computes the complete softmax, normalizes in-kernel, and writes the
// proj A-matrix directly as bf16 hi/lo [5760][256] (same layout as Qhl).
// LDS 34.6 KB -> 4 blocks/CU.
// ---------------------------------------------------------------------------
__global__ __launch_bounds__(256, 4) void attn_kernel(
    const unsigned short* __restrict__ Qhl,   // [5760][256] bf16 per-head hi|lo
    const unsigned short* __restrict__ Kbf,   // [5760][128] bf16
    const unsigned short* __restrict__ Vbf,   // [5760][128] bf16
    unsigned short* __restrict__ Ahl)         // [5760][256] bf16 per-head hi|lo
{
    // LDS layout:
    //   Vt   : ushort[16][520]      @     0  (16640 B)  V^T all 512 u-slots
    //   Qb   : ushort[80][40]       @ 16640  ( 6400 B)
    //   Pw   : ushort[4][2][16][40] @ 23040  (10240 B)
    //   red_l: float[4][80]         @ 33280  ( 1280 B)
    //   redO : float[320][16]       @     0  (20480 B) overlay post-barrier
    __shared__ __align__(16) char smem[34560];
    unsigned short (*Vt)[520] = (unsigned short(*)[520])smem;
    unsigned short (*Qb)[40]  = (unsigned short(*)[40])(smem + 16640);
    unsigned short* PwBase    = (unsigned short*)(smem + 23040);
    float* red_l              = (float*)(smem + 33280);
    float* redO               = (float*)smem;

    const int tile = blockIdx.x;
    const int h    = blockIdx.y;
    const int ty0  = (tile / 12) * 4;
    const int tx0  = (tile % 12) * 4;
    const int tid  = threadIdx.x;

    // ---- stage V^T for all 512 u-slots (500 real, rest zero) ----
    for (int i = tid; i < 1024; i += 256) {
        const int ul = i >> 1, hf8 = i & 1;
        if (ul < 500) {
            const int dp = ul / 100;
            const int rr = ul - dp * 100;
            const int yy = rr / 10;
            const int xx = rr - yy * 10;
            int y = ty0 - 3 + yy; if (y < 0) y += HH;  if (y >= HH) y -= HH;
            int x = tx0 - 3 + xx; if (x < 0) x += WW_; if (x >= WW_) x -= WW_;
            const int g = (dp * HH + y) * WW_ + x;
            const bf16x8 v = *(const bf16x8*)(Vbf + (size_t)g * 128 + h * 16 + hf8 * 8);
            #pragma unroll
            for (int c = 0; c < 8; ++c) Vt[hf8 * 8 + c][ul] = (unsigned short)v[c];
        } else {
            #pragma unroll
            for (int c = 0; c < 8; ++c) Vt[hf8 * 8 + c][ul] = 0;
        }
    }
    // ---- stage Q tile (straight bf16 copy) ----
    for (int i = tid; i < 320; i += 256) {
        const int p = i >> 2, seg = i & 3;
        const int d = p >> 4, s = p & 15;
        const int sy = s >> 2, sx = s & 3;
        const int g = (d * HH + ty0 + sy) * WW_ + tx0 + sx;
        *(bf16x8*)(&Qb[p][seg * 8]) = *(const bf16x8*)(Qhl + (size_t)g * 256 + h * 32 + seg * 8);
    }
    __syncthreads();

    const int w    = tid >> 6;
    const int lane = tid & 63;
    const int ln   = lane & 15;
    const int quad = lane >> 4;
    const int sy   = ln >> 2, sx = ln & 3;

    unsigned short* Pw = PwBase + w * 1280;  // [2][16][40]

    bf16x8 qf[5];
    #pragma unroll
    for (int mt = 0; mt < 5; ++mt)
        qf[mt] = *(const bf16x8*)(&Qb[mt * 16 + ln][quad * 8]);

    f32x4 Ow[5] = {};
    float lsum[5] = {};

    #pragma unroll
    for (int chunk = 0; chunk < 4; ++chunk) {
        const int u0 = (w * 4 + chunk) * 32;   // u base (global == LDS-local now)

        int rowa, rowb;
        {
            const int ua = u0 + ln      < 500 ? u0 + ln      : 499;
            const int ub = u0 + 16 + ln < 500 ? u0 + 16 + ln : 499;
            int dp = ua / 100, rr = ua - dp * 100, yy = rr / 10, xx = rr - yy * 10;
            int y = ty0 - 3 + yy; if (y < 0) y += HH;  if (y >= HH) y -= HH;
            int x = tx0 - 3 + xx; if (x < 0) x += WW_; if (x >= WW_) x -= WW_;
            rowa = (dp * HH + y) * WW_ + x;
            dp = ub / 100; rr = ub - dp * 100; yy = rr / 10; xx = rr - yy * 10;
            y = ty0 - 3 + yy; if (y < 0) y += HH;  if (y >= HH) y -= HH;
            x = tx0 - 3 + xx; if (x < 0) x += WW_; if (x >= WW_) x -= WW_;
            rowb = (dp * HH + y) * WW_ + x;
        }
        const bf16x8 ka = *(const bf16x8*)(Kbf + (size_t)rowa * 128 + h * 16 + (quad & 1) * 8);
        const bf16x8 kb = *(const bf16x8*)(Kbf + (size_t)rowb * 128 + h * 16 + (quad & 1) * 8);

        bool msk[2][4];
        #pragma unroll
        for (int b = 0; b < 2; ++b)
            #pragma unroll
            for (int r = 0; r < 4; ++r) {
                const int u = u0 + 16 * b + 4 * quad + r;
                const int rr = u % 100;
                const int uy = rr / 10, ux = rr - uy * 10;
                msk[b][r] = (u < 500) && ((unsigned)(uy - sy) <= 6u)
                                      && ((unsigned)(ux - sx) <= 6u);
            }

        const bf16x8 vf = *(const bf16x8*)(&Vt[ln][u0 + quad * 8]);

        #pragma unroll
        for (int mt = 0; mt < 5; ++mt) {
            f32x4 s0 = __builtin_amdgcn_mfma_f32_16x16x32_bf16(
                ka, qf[mt], (f32x4){0.f, 0.f, 0.f, 0.f}, 0, 0, 0);
            f32x4 s1 = __builtin_amdgcn_mfma_f32_16x16x32_bf16(
                kb, qf[mt], (f32x4){0.f, 0.f, 0.f, 0.f}, 0, 0, 0);

            unsigned short* pw = Pw + (mt & 1) * 640 + ln * 40;
            #pragma unroll
            for (int b = 0; b < 2; ++b) {
                const f32x4 s = b ? s1 : s0;
                float ev[4];
                #pragma unroll
                for (int r = 0; r < 4; ++r)
                    ev[r] = msk[b][r] ? __expf(fmaf(s[r], SCALE, -8.0f)) : 0.f;
                const unsigned p01 = cvt_pk_bf16(ev[0], ev[1]);
                const unsigned p23 = cvt_pk_bf16(ev[2], ev[3]);
                lsum[mt] += bfpk_lo(p01) + bfpk_hi(p01) + bfpk_lo(p23) + bfpk_hi(p23);
                *(unsigned*)(pw + 16 * b + 4 * quad)     = p01;
                *(unsigned*)(pw + 16 * b + 4 * quad + 2) = p23;
            }
            const bf16x8 pf = *(const bf16x8*)(Pw + (mt & 1) * 640 + ln * 40 + quad * 8);
            Ow[mt] = __builtin_amdgcn_mfma_f32_16x16x32_bf16(vf, pf, Ow[mt], 0, 0, 0);
        }
    }

    // l: lanes (ln, quad) hold disjoint u-partials -> reduce across quads
    #pragma unroll
    for (int mt = 0; mt < 5; ++mt) {
        lsum[mt] += __shfl_xor(lsum[mt], 16);
        lsum[mt] += __shfl_xor(lsum[mt], 32);
    }

    __syncthreads();   // all Vt/Qb/Pw reads done; safe to overlay redO

    if (quad == 0) {
        #pragma unroll
        for (int mt = 0; mt < 5; ++mt)
            red_l[w * 80 + mt * 16 + ln] = lsum[mt];
    }
    #pragma unroll
    for (int mt = 0; mt < 5; ++mt)
        #pragma unroll
        for (int r = 0; r < 4; ++r)
            redO[(size_t)((w * 5 + mt) * 16 + quad * 4 + r) * 16 + ln] = Ow[mt][r];
    __syncthreads();

    // final: sum 4 wave-partials, normalize, write bf16 hi/lo A-matrix
    for (int i = tid; i < 1280; i += 256) {
        const int m = i >> 4, c = i & 15;
        const int mt = m >> 4, mloc = m & 15;
        float o = 0.f, l = 0.f;
        #pragma unroll
        for (int w4 = 0; w4 < 4; ++w4) {
            o += redO[(size_t)((w4 * 5 + mt) * 16 + c) * 16 + mloc];
            l += red_l[w4 * 80 + m];
        }
        const float val = o / l;
        const int qsy = (mloc >> 2), qsx = mloc & 3;
        const size_t g = (size_t)((mt * HH + ty0 + qsy) * WW_ + (tx0 + qsx));
        const unsigned short hi = f2bf(val);
        Ahl[g * 256 + h * 32 + c]      = hi;
        Ahl[g * 256 + h * 32 + 16 + c] = f2bf(val - bf2f(hi));
    }
}

// ---------------------------------------------------------------------------
extern "C" void kernel_launch(void* const* d_in, const int* in_sizes, int n_in,
                              void* d_out, int out_size, void* d_ws, size_t ws_size,
                              hipStream_t stream)
{
    const float* x      = (const float*)d_in[0];
    const float* qkv_w  = (const float*)d_in[1];
    const float* qkv_b  = (const float*)d_in[2];
    const float* proj_w = (const float*)d_in[3];
    const float* proj_b = (const float*)d_in[4];
    float* out = (float*)d_out;

    char* ws = (char*)d_ws;
    unsigned short* Qhl = (unsigned short*)ws;  ws += (size_t)NPOS * 256 * 2;
    unsigned short* Kbf = (unsigned short*)ws;  ws += (size_t)NPOS * 128 * 2;
    unsigned short* Vbf = (unsigned short*)ws;  ws += (size_t)NPOS * 128 * 2;
    unsigned short* Ahl = (unsigned short*)ws;  ws += (size_t)NPOS * 256 * 2;

    // 1. QKV GEMM (fused fp32->hi/lo conversion) -> Qhl, Kbf, Vbf
    {
        dim3 grid(384 / 64, NPOS / 64);
        gemm_qkv_kernel<<<grid, 256, 0, stream>>>(x, qkv_w, qkv_b, Qhl, Kbf, Vbf);
    }
    // 2. fused neighborhood attention (full u-range, 576 blocks) -> Ahl
    {
        dim3 grid(72, NHEADS);
        attn_kernel<<<grid, 256, 0, stream>>>(Qhl, Kbf, Vbf, Ahl);
    }
    // 3. proj GEMM (A pre-normalized bf16 hi/lo) -> out
    {
        dim3 grid(DIMC / 64, NPOS / 64);
        gemm_proj_kernel<<<grid, 256, 0, stream>>>(Ahl, proj_w, proj_b, out);
    }
}